// Round 5
// baseline (6491.986 us; speedup 1.0000x reference)
//
#include <hip/hip_runtime.h>
#include <math.h>

#define T_LEN 512
#define BATCH 128
#define HID   256
#define BH    (BATCH*HID)   // 32768

// ---------------- helpers ----------------
// fast reciprocal: v_rcp_f32 + 1 Newton step (~0.5 ulp, cheaper than exact div)
__device__ __forceinline__ float frcp(float d) {
    float r = __builtin_amdgcn_rcpf(d);
    return r * fmaf(-d, r, 2.0f);
}
__device__ __forceinline__ float sigmoid_f(float v) {
    return frcp(1.f + __expf(-v));
}
__device__ __forceinline__ float tanh_f(float v) {
    v = fminf(fmaxf(v, -15.f), 15.f);
    const float e = __expf(2.f * v);
    return (e - 1.f) * frcp(e + 1.f);
}
__device__ __forceinline__ float4 ldf4(const float* p) {
    return *reinterpret_cast<const float4*>(p);
}
__device__ __forceinline__ void fma4(float4& a, const float4 v, const float4 w) {
    a.x = fmaf(v.x, w.x, a.x);
    a.y = fmaf(v.y, w.y, a.y);
    a.z = fmaf(v.z, w.z, a.z);
    a.w = fmaf(v.w, w.w, a.w);
}
__device__ __forceinline__ float hsum4(const float4 a) {
    return (a.x + a.y) + (a.z + a.w);
}
// Pin weights into VGPRs (asm def can't be rematerialized into the loop).
// R2 lesson: do NOT force AGPRs (accvgpr_read copies at uses).
// R4 lesson: do NOT hand-write v_pk_fma (operand-pair moves + scheduling loss).
__device__ __forceinline__ void pin4(float4& v) {
    asm volatile("" : "+v"(v.x), "+v"(v.y), "+v"(v.z), "+v"(v.w));
}
// agent-scope relaxed atomics: coherent across XCDs, no cache flushes
__device__ __forceinline__ void astore(float* p, float v) {
    __hip_atomic_store(p, v, __ATOMIC_RELAXED, __HIP_MEMORY_SCOPE_AGENT);
}
__device__ __forceinline__ float2 af2(const float* p) {
    unsigned long long u = __hip_atomic_load((const unsigned long long*)p,
                                             __ATOMIC_RELAXED, __HIP_MEMORY_SCOPE_AGENT);
    union { unsigned long long u; float2 f; } c; c.u = u;
    return c.f;
}
__device__ __forceinline__ float4 af4(const float* p) {
    const float2 a = af2(p), b = af2(p + 2);
    return make_float4(a.x, a.y, b.x, b.y);
}
// DPP row_shr prefix reduction within 16-lane groups; lane (kc==15) gets the sum.
template<int CTRL>
__device__ __forceinline__ float dpp_mv(float x) {
    return __int_as_float(__builtin_amdgcn_update_dpp(
        0, __float_as_int(x), CTRL, 0xF, 0xF, true));
}
__device__ __forceinline__ float red16(float x) {
    x += dpp_mv<0x111>(x);  // row_shr:1
    x += dpp_mv<0x112>(x);  // row_shr:2
    x += dpp_mv<0x114>(x);  // row_shr:4
    x += dpp_mv<0x118>(x);  // row_shr:8
    return x;               // valid in lane kc==15 of each 16-group
}

// ---------------- persistent LSTM (R1 skeleton + proven deltas) ----------------
// grid 512 x 256, 2 blocks/CU, IDENTITY decode (bg = bid&15 keeps each
// 32-block bg-group on one XCD; R2 proved breaking this costs 6.7x FETCH).
// Sync = R1 verbatim: block flags (32/bg-group), 32 poller lanes, 4 barriers.
// R3 proved wide polling causes coherence-fabric congestion collapse.
//
// Schedule: L0 computes h0[s-1] at iter s (lag 1); L1 computes h1[s-3] (lag 3).
// Per iter: poll -> B1 -> stage [x|h] -> B2 -> critical K=256 recurrent GEMV
// (+ register-carried input-half partials ax[] + bias, owner lane -> ls_a)
// -> B3 -> block epilogue (tid<128, c in register, COALESCED h stores)
// -> B4 -> tid0 publishes flag -> input-half K=256 GEMV for next step into
// ax[] registers (slack work inside the publish->poll window; no reduce).
//
// LDS (R4-proven layout): col c of combined K=512 -> row c>>4 (32 rows),
// offset c&15, row stride 20 floats (16B-aligned b128; 8x fewer bank
// conflicts than the R1 layout: 2.68e8 -> 3.36e7). Single-buffered: B4/B1
// separate this iter's xact reads from next iter's staging writes.
__global__ __launch_bounds__(256)
__attribute__((amdgpu_waves_per_eu(2, 2)))
void lstm_persist(
    const float* __restrict__ x,
    const float* __restrict__ Wih, const float* __restrict__ Whh,
    const float* __restrict__ bih, const float* __restrict__ bhh,
    float* __restrict__ out,
    float* __restrict__ h0buf,   // 3 * BH (triple-buffered by timestep%3)
    float* __restrict__ h1buf,   // 3 * BH
    int* __restrict__ flags)     // 16 bg-groups x 32 block flags
{
    __shared__ float ls_in[8 * 640];   // 20.5 KiB, stride-20 rows
    __shared__ float ls_a [128 * 4];   // gate pre-activations [b*16+jp][g]

    const int tid = threadIdx.x;
    const int bid = blockIdx.x;
    const int bg = bid & 15;
    const int layer = (bid >> 4) & 1;
    const int jt = bid >> 5;
    const int jp = tid >> 4;
    const int kc = tid & 15;
    const int j = jt * 16 + jp;
    const int Bg0 = bg * 8;

    const float* Wih_l = Wih + (size_t)layer * 4 * HID * HID;
    const float* Whh_l = Whh + (size_t)layer * 4 * HID * HID;
    const float* bih_l = bih + layer * 4 * HID;
    const float* bhh_l = bhh + layer * 4 * HID;

    // Weights: 4 gates x 16 K-cols per half = 128 floats, pinned VGPRs.
    float4 wih[4][4], whh[4][4];
    float bias[4];
    #pragma unroll
    for (int g = 0; g < 4; ++g) {
        const int row = g * HID + j;             // row in 4H
        const float* pih = Wih_l + (size_t)row * HID + kc * 16;
        const float* phh = Whh_l + (size_t)row * HID + kc * 16;
        #pragma unroll
        for (int m = 0; m < 4; ++m) {
            wih[g][m] = ldf4(pih + m * 4);
            pin4(wih[g][m]);
            whh[g][m] = ldf4(phh + m * 4);
            pin4(whh[g][m]);
        }
        bias[g] = bih_l[row] + bhh_l[row];
        asm volatile("" : "+v"(bias[g]));
    }

    // Register-carried state: input-half partials (all lanes, reduced jointly
    // with crit next iter) and cell state (tid<128: thread = fixed cell).
    float ax[8][4];
    #pragma unroll
    for (int b = 0; b < 8; ++b) {
        #pragma unroll
        for (int g = 0; g < 4; ++g) ax[b][g] = 0.f;
    }
    float c_reg = 0.f;

    int* myflag = flags + bg * 32 + layer * 16 + jt;

    #pragma unroll 1
    for (int s = 0; s <= T_LEN + 2; ++s) {
        if (s > 0 && tid < 32) {
            // signed compare: 0xAAAAAAAA poison is negative -> blocks until real store
            const int thr = (layer == 0 && tid >= 16) ? (s - 1) : s;
            const int* f = flags + bg * 32 + tid;
            while (__hip_atomic_load(f, __ATOMIC_RELAXED, __HIP_MEMORY_SCOPE_AGENT) < thr)
                __builtin_amdgcn_s_sleep(1);
        }
        __syncthreads();   // B1: inputs published & visible

        // crit: compute h[t] (t = s-1 for L0, s-3 for L1) from recurrent half.
        // xact: input-half partial sums for the step after t (per-lane, regs).
        const bool crit = (layer == 0) ? (s >= 1 && s <= T_LEN) : (s >= 3);
        const bool xact = (layer == 0) ? (s < T_LEN) : (s >= 2 && s <= T_LEN + 1);
        const bool zeroh = (layer == 0) ? (s == 1) : (s == 3);   // h[t-1] = 0

        if (crit || xact) {
            // cols 0..255 = input half | 256..511 = recurrent half
            const float* ph0 = h0buf + (size_t)((s + 1) % 3) * BH;  // h0[s-2]
            const float* ph1 = h1buf + (size_t)((s + 2) % 3) * BH;  // h1[s-4]
            #pragma unroll
            for (int i = 0; i < 4; ++i) {
                const int F = tid + 256 * i;     // f4 index in 8 b x 128
                const int b = F >> 7;
                const int rr = F & 127;          // global col = rr*4
                const size_t row = (size_t)(Bg0 + b) * HID + (rr & 63) * 4;
                float4 v = make_float4(0.f, 0.f, 0.f, 0.f);
                if ((rr >> 6) == 0) {            // input half (slack)
                    if (xact)
                        v = (layer == 0) ? ldf4(x + (size_t)s * BH + row)
                                         : af4(ph0 + row);
                } else if (crit && !zeroh) {     // recurrent half (critical)
                    v = (layer == 0) ? af4(ph0 + row) : af4(ph1 + row);
                }
                // col 4rr -> row rr>>2, float-off (rr&3)*4; row stride 20
                *(float4*)(ls_in + b * 640 + (rr >> 2) * 20 + (rr & 3) * 4) = v;
            }
        }
        __syncthreads();   // B2: staging visible to all waves

        if (crit) {
            // ---- CRITICAL: recurrent K=256 GEMV + joint reduce with carried ax
            // lane kc chunk: cols 256+16kc..+15 -> row 16+kc
            #pragma unroll 2
            for (int b = 0; b < 8; ++b) {
                const float4* Lp = (const float4*)(ls_in + b * 640 + (16 + kc) * 20);
                const float4 i0 = Lp[0], i1 = Lp[1], i2 = Lp[2], i3 = Lp[3];
                float4 ac[4];
                #pragma unroll
                for (int g = 0; g < 4; ++g) ac[g] = make_float4(0.f, 0.f, 0.f, 0.f);
                #pragma unroll
                for (int g = 0; g < 4; ++g) {
                    fma4(ac[g], i0, whh[g][0]);
                    fma4(ac[g], i1, whh[g][1]);
                    fma4(ac[g], i2, whh[g][2]);
                    fma4(ac[g], i3, whh[g][3]);
                }
                // add carried input-half partial BEFORE the cross-lane reduce
                const float r0 = red16(hsum4(ac[0]) + ax[b][0]);
                const float r1 = red16(hsum4(ac[1]) + ax[b][1]);
                const float r2 = red16(hsum4(ac[2]) + ax[b][2]);
                const float r3 = red16(hsum4(ac[3]) + ax[b][3]);
                if (kc == 15) {        // owner lane: publish pre-activations (+bias)
                    float* ap = ls_a + (b * 16 + jp) * 4;
                    ap[0] = r0 + bias[0];
                    ap[1] = r1 + bias[1];
                    ap[2] = r2 + bias[2];
                    ap[3] = r3 + bias[3];
                }
            }
        }
        __syncthreads();   // B3: ls_a complete

        if (crit && tid < 128) {
            // ---- block epilogue: thread = one (b, j) cell; COALESCED stores
            const int bb = tid >> 4;
            const int jpp = tid & 15;
            const int t = (layer == 0) ? (s - 1) : (s - 3);
            float* hst = (layer == 0) ? (h0buf + (size_t)((s + 2) % 3) * BH)  // h0[s-1]
                                      : (h1buf + (size_t)(s % 3) * BH);       // h1[s-3]
            const bool last = (t == T_LEN - 1);
            const float* ap = ls_a + tid * 4;
            const float gi = sigmoid_f(ap[0]);
            const float gf = sigmoid_f(ap[1]);
            const float gg = tanh_f   (ap[2]);
            const float go = sigmoid_f(ap[3]);
            const float cnew = fmaf(gf, c_reg, gi * gg);
            c_reg = cnew;
            const float h = go * tanh_f(cnew);
            const int B = Bg0 + bb;
            const int jg = jt * 16 + jpp;
            astore(hst + (size_t)B * HID + jg, h);
            if (layer == 1)
                out[(size_t)t * BH + (size_t)B * HID + jg] = h;
            if (last) {
                float* hn  = out + (size_t)T_LEN * BH;
                float* cnp = hn + 2 * BH;
                hn [(size_t)layer * BH + (size_t)B * HID + jg] = h;
                cnp[(size_t)layer * BH + (size_t)B * HID + jg] = cnew;
            }
        }
        __syncthreads();   // B4: h-stores drained (vmcnt(0) before s_barrier)
        if (s <= T_LEN + 1 && tid == 0)
            __hip_atomic_store(myflag, s + 1, __ATOMIC_RELAXED, __HIP_MEMORY_SCOPE_AGENT);

        if (xact) {
            // ---- SLACK: input-half K=256 GEMV for the NEXT step, after the
            // flag is out. Per-lane partials only; no reduce, no LDS writes.
            // lane kc chunk: cols 16kc..+15 -> row kc
            #pragma unroll 2
            for (int b = 0; b < 8; ++b) {
                const float4* Lp = (const float4*)(ls_in + b * 640 + kc * 20);
                const float4 i0 = Lp[0], i1 = Lp[1], i2 = Lp[2], i3 = Lp[3];
                float4 ac[4];
                #pragma unroll
                for (int g = 0; g < 4; ++g) ac[g] = make_float4(0.f, 0.f, 0.f, 0.f);
                #pragma unroll
                for (int g = 0; g < 4; ++g) {
                    fma4(ac[g], i0, wih[g][0]);
                    fma4(ac[g], i1, wih[g][1]);
                    fma4(ac[g], i2, wih[g][2]);
                    fma4(ac[g], i3, wih[g][3]);
                }
                #pragma unroll
                for (int g = 0; g < 4; ++g) ax[b][g] = hsum4(ac[g]);
            }
        }
    }
}

extern "C" void kernel_launch(void* const* d_in, const int* in_sizes, int n_in,
                              void* d_out, int out_size, void* d_ws, size_t ws_size,
                              hipStream_t stream) {
    const float* x   = (const float*)d_in[0];
    const float* Wih = (const float*)d_in[1];
    const float* Whh = (const float*)d_in[2];
    const float* bih = (const float*)d_in[3];
    const float* bhh = (const float*)d_in[4];
    float* out = (float*)d_out;

    float* h0 = (float*)d_ws;          // 3*BH
    float* h1 = h0 + 3 * BH;           // 3*BH
    int* flags = (int*)(h1 + 3 * BH);  // 512 ints, poison-proof (signed compare)

    hipLaunchKernelGGL(lstm_persist, dim3(512), dim3(256), 0, stream,
                       x, Wih, Whh, bih, bhh, out, h0, h1, flags);
}

// Round 6
// 3590.979 us; speedup vs baseline: 1.8079x; 1.8079x over previous
//
#include <hip/hip_runtime.h>
#include <math.h>

#define T_LEN 512
#define BATCH 128
#define HID   256
#define BH    (BATCH*HID)   // 32768

// ---------------- helpers ----------------
// fast reciprocal: v_rcp_f32 + 1 Newton step (~0.5 ulp, cheaper than exact div)
__device__ __forceinline__ float frcp(float d) {
    float r = __builtin_amdgcn_rcpf(d);
    return r * fmaf(-d, r, 2.0f);
}
__device__ __forceinline__ float sigmoid_f(float v) {
    return frcp(1.f + __expf(-v));
}
__device__ __forceinline__ float tanh_f(float v) {
    v = fminf(fmaxf(v, -15.f), 15.f);
    const float e = __expf(2.f * v);
    return (e - 1.f) * frcp(e + 1.f);
}
__device__ __forceinline__ float4 ldf4(const float* p) {
    return *reinterpret_cast<const float4*>(p);
}
__device__ __forceinline__ void fma4(float4& a, const float4 v, const float4 w) {
    a.x = fmaf(v.x, w.x, a.x);
    a.y = fmaf(v.y, w.y, a.y);
    a.z = fmaf(v.z, w.z, a.z);
    a.w = fmaf(v.w, w.w, a.w);
}
__device__ __forceinline__ float hsum4(const float4 a) {
    return (a.x + a.y) + (a.z + a.w);
}
// Pin weights into VGPRs (asm def can't be rematerialized into the loop).
// R2: no AGPR forcing. R4: no hand-written pk_fma. R5: no extra register-
// carried loop state (ax/c in regs) — it spills to scratch -> HBM blowup.
__device__ __forceinline__ void pin4(float4& v) {
    asm volatile("" : "+v"(v.x), "+v"(v.y), "+v"(v.z), "+v"(v.w));
}
// agent-scope relaxed atomics: coherent across XCDs, no cache flushes
__device__ __forceinline__ void astore(float* p, float v) {
    __hip_atomic_store(p, v, __ATOMIC_RELAXED, __HIP_MEMORY_SCOPE_AGENT);
}
__device__ __forceinline__ float2 af2(const float* p) {
    unsigned long long u = __hip_atomic_load((const unsigned long long*)p,
                                             __ATOMIC_RELAXED, __HIP_MEMORY_SCOPE_AGENT);
    union { unsigned long long u; float2 f; } c; c.u = u;
    return c.f;
}
__device__ __forceinline__ float4 af4(const float* p) {
    const float2 a = af2(p), b = af2(p + 2);
    return make_float4(a.x, a.y, b.x, b.y);
}
// DPP row_shr prefix reduction within 16-lane groups; lane (kc==15) gets the sum.
template<int CTRL>
__device__ __forceinline__ float dpp_mv(float x) {
    return __int_as_float(__builtin_amdgcn_update_dpp(
        0, __float_as_int(x), CTRL, 0xF, 0xF, true));
}
__device__ __forceinline__ float red16(float x) {
    x += dpp_mv<0x111>(x);  // row_shr:1
    x += dpp_mv<0x112>(x);  // row_shr:2
    x += dpp_mv<0x114>(x);  // row_shr:4
    x += dpp_mv<0x118>(x);  // row_shr:8
    return x;               // valid in lane kc==15 of each 16-group
}

// ---------------- persistent LSTM (R1 skeleton, stride-20 LDS) ----------------
// grid 512 x 256, 2 blocks/CU, IDENTITY decode (bg = bid&15 keeps each
// 32-block bg-group on one XCD; R2 proved breaking this costs 6.7x FETCH).
// Sync = R1 verbatim: block flags (32/bg-group), 32 poller lanes, 4 barriers.
// All per-step state (ls_ax, ls_c, ls_a) stays in LDS — R5 proved moving it
// to registers triggers scratch spills (FETCH 119 MB -> 4.26 GB).
//
// Schedule: L0 computes h0[s-1] at iter s (lag 1); L1 computes h1[s-3] (lag 3).
// Per iter: poll -> B1 -> stage [x|h] -> B2 -> critical K=256 recurrent GEMV
// (+ ls_ax partials from last iter + bias, owner lane -> ls_a) -> B3 ->
// block epilogue (tid<128, c in ls_c, coalesced stores) -> B4 -> tid0
// publishes flag -> input-half K=256 GEMV for the next step into ls_ax
// (slack work inside the publish->poll window).
//
// LDS layout (the ONLY change vs R1, proven in R4/R5): col c of combined
// K=512 -> row c>>4 (32 rows), offset c&15, row stride 20 floats. All
// accesses are 16B-aligned ds_*_b128 at 80B lane stride -> worst 2-way bank
// alias (free). Measured: conflicts 2.68e8 -> 3.36e7.
__global__ __launch_bounds__(256)
__attribute__((amdgpu_waves_per_eu(2, 2)))
void lstm_persist(
    const float* __restrict__ x,
    const float* __restrict__ Wih, const float* __restrict__ Whh,
    const float* __restrict__ bih, const float* __restrict__ bhh,
    float* __restrict__ out,
    float* __restrict__ h0buf,   // 3 * BH (triple-buffered by timestep%3)
    float* __restrict__ h1buf,   // 3 * BH
    int* __restrict__ flags)     // 16 groups x 32 blocks
{
    __shared__ float ls_in[8 * 640];   // 8 b x 32 rows x 20 (stride-20)
    __shared__ float ls_a [128 * 4];   // gate pre-activations [b*16+jp][g]
    __shared__ float ls_ax[128 * 4];   // input-half sums for NEXT step
    __shared__ float ls_c [128];       // c[b*16+jp]

    const int tid = threadIdx.x;
    const int bid = blockIdx.x;
    const int bg = bid & 15;
    const int layer = (bid >> 4) & 1;
    const int jt = bid >> 5;
    const int jp = tid >> 4;
    const int kc = tid & 15;
    const int j = jt * 16 + jp;
    const int Bg0 = bg * 8;

    const float* Wih_l = Wih + (size_t)layer * 4 * HID * HID;
    const float* Whh_l = Whh + (size_t)layer * 4 * HID * HID;
    const float* bih_l = bih + layer * 4 * HID;
    const float* bhh_l = bhh + layer * 4 * HID;

    // Weights: 4 gates x 16 K-cols per half = 128 floats, pinned VGPRs.
    float4 wih[4][4], whh[4][4];
    float bias[4];
    #pragma unroll
    for (int g = 0; g < 4; ++g) {
        const int row = g * HID + j;             // row in 4H
        const float* pih = Wih_l + (size_t)row * HID + kc * 16;
        const float* phh = Whh_l + (size_t)row * HID + kc * 16;
        #pragma unroll
        for (int m = 0; m < 4; ++m) {
            wih[g][m] = ldf4(pih + m * 4);
            pin4(wih[g][m]);
            whh[g][m] = ldf4(phh + m * 4);
            pin4(whh[g][m]);
        }
        bias[g] = bih_l[row] + bhh_l[row];
        asm volatile("" : "+v"(bias[g]));
    }

    if (tid < 128) {                   // synced by first barrier below
        ls_c[tid] = 0.f;
        #pragma unroll
        for (int g = 0; g < 4; ++g) ls_ax[tid * 4 + g] = 0.f;
    }

    int* myflag = flags + bg * 32 + layer * 16 + jt;

    #pragma unroll 1
    for (int s = 0; s <= T_LEN + 2; ++s) {
        if (s > 0 && tid < 32) {
            // signed compare: 0xAAAAAAAA poison is negative -> blocks until real store
            const int thr = (layer == 0 && tid >= 16) ? (s - 1) : s;
            const int* f = flags + bg * 32 + tid;
            while (__hip_atomic_load(f, __ATOMIC_RELAXED, __HIP_MEMORY_SCOPE_AGENT) < thr)
                __builtin_amdgcn_s_sleep(1);
        }
        __syncthreads();   // B1: inputs published & visible

        // crit: compute h[t] (t = s-1 for L0, s-3 for L1) from recurrent half.
        // xact: input-half partial sums for the step after t (-> ls_ax).
        const bool crit = (layer == 0) ? (s >= 1 && s <= T_LEN) : (s >= 3);
        const bool xact = (layer == 0) ? (s < T_LEN) : (s >= 2 && s <= T_LEN + 1);
        const bool zeroh = (layer == 0) ? (s == 1) : (s == 3);   // h[t-1] = 0

        if (crit || xact) {
            // cols 0..255 = input half | 256..511 = recurrent half
            const float* ph0 = h0buf + (size_t)((s + 1) % 3) * BH;  // h0[s-2]
            const float* ph1 = h1buf + (size_t)((s + 2) % 3) * BH;  // h1[s-4]
            #pragma unroll
            for (int i = 0; i < 4; ++i) {
                const int F = tid + 256 * i;     // f4 index in 8 b x 128
                const int b = F >> 7;
                const int rr = F & 127;          // global col = rr*4
                const size_t row = (size_t)(Bg0 + b) * HID + (rr & 63) * 4;
                float4 v = make_float4(0.f, 0.f, 0.f, 0.f);
                if ((rr >> 6) == 0) {            // input half (slack)
                    if (xact)
                        v = (layer == 0) ? ldf4(x + (size_t)s * BH + row)
                                         : af4(ph0 + row);
                } else if (crit && !zeroh) {     // recurrent half (critical)
                    v = (layer == 0) ? af4(ph0 + row) : af4(ph1 + row);
                }
                // col 4rr -> row rr>>2, float-off (rr&3)*4; row stride 20
                *(float4*)(ls_in + b * 640 + (rr >> 2) * 20 + (rr & 3) * 4) = v;
            }
        }
        __syncthreads();   // B2: staging visible

        if (crit) {
            // ---- CRITICAL: recurrent K=256 GEMV; lane kc -> row 16+kc
            #pragma unroll 2
            for (int b = 0; b < 8; ++b) {
                const float4* Lp = (const float4*)(ls_in + b * 640 + (16 + kc) * 20);
                const float4 i0 = Lp[0], i1 = Lp[1], i2 = Lp[2], i3 = Lp[3];
                float4 ac[4];
                #pragma unroll
                for (int g = 0; g < 4; ++g) ac[g] = make_float4(0.f, 0.f, 0.f, 0.f);
                #pragma unroll
                for (int g = 0; g < 4; ++g) {
                    fma4(ac[g], i0, whh[g][0]);
                    fma4(ac[g], i1, whh[g][1]);
                    fma4(ac[g], i2, whh[g][2]);
                    fma4(ac[g], i3, whh[g][3]);
                }
                const float a0 = red16(hsum4(ac[0]));
                const float a1 = red16(hsum4(ac[1]));
                const float a2 = red16(hsum4(ac[2]));
                const float a3 = red16(hsum4(ac[3]));
                if (kc == 15) {   // owner: combine with input-half sums from last iter
                    const int cell = b * 16 + jp;
                    const float* axp = ls_ax + cell * 4;
                    float* ap = ls_a + cell * 4;
                    ap[0] = a0 + bias[0] + axp[0];
                    ap[1] = a1 + bias[1] + axp[1];
                    ap[2] = a2 + bias[2] + axp[2];
                    ap[3] = a3 + bias[3] + axp[3];
                }
            }
        }
        __syncthreads();   // B3: ls_a complete

        if (crit && tid < 128) {
            // ---- block epilogue: thread = one (b, j) cell; coalesced stores
            const int bb = tid >> 4;
            const int jpp = tid & 15;
            const int t = (layer == 0) ? (s - 1) : (s - 3);
            float* hst = (layer == 0) ? (h0buf + (size_t)((s + 2) % 3) * BH)  // h0[s-1]
                                      : (h1buf + (size_t)(s % 3) * BH);       // h1[s-3]
            const bool last = (t == T_LEN - 1);
            const float* ap = ls_a + tid * 4;
            const float gi = sigmoid_f(ap[0]);
            const float gf = sigmoid_f(ap[1]);
            const float gg = tanh_f   (ap[2]);
            const float go = sigmoid_f(ap[3]);
            const float cold = ls_c[tid];
            const float cnew = fmaf(gf, cold, gi * gg);
            ls_c[tid] = cnew;
            const float h = go * tanh_f(cnew);
            const int B = Bg0 + bb;
            const int jg = jt * 16 + jpp;
            astore(hst + (size_t)B * HID + jg, h);
            if (layer == 1)
                out[(size_t)t * BH + (size_t)B * HID + jg] = h;
            if (last) {
                float* hn  = out + (size_t)T_LEN * BH;
                float* cnp = hn + 2 * BH;
                hn [(size_t)layer * BH + (size_t)B * HID + jg] = h;
                cnp[(size_t)layer * BH + (size_t)B * HID + jg] = cnew;
            }
        }
        __syncthreads();   // B4: h-stores drained (vmcnt(0) before s_barrier)
        if (s <= T_LEN + 1 && tid == 0)
            __hip_atomic_store(myflag, s + 1, __ATOMIC_RELAXED, __HIP_MEMORY_SCOPE_AGENT);

        if (xact) {
            // ---- SLACK: input-half K=256 GEMV for the NEXT step, after the
            // flag is out. lane kc -> row kc; owner writes ls_ax.
            #pragma unroll 2
            for (int b = 0; b < 8; ++b) {
                const float4* Lp = (const float4*)(ls_in + b * 640 + kc * 20);
                const float4 i0 = Lp[0], i1 = Lp[1], i2 = Lp[2], i3 = Lp[3];
                float4 ac[4];
                #pragma unroll
                for (int g = 0; g < 4; ++g) ac[g] = make_float4(0.f, 0.f, 0.f, 0.f);
                #pragma unroll
                for (int g = 0; g < 4; ++g) {
                    fma4(ac[g], i0, wih[g][0]);
                    fma4(ac[g], i1, wih[g][1]);
                    fma4(ac[g], i2, wih[g][2]);
                    fma4(ac[g], i3, wih[g][3]);
                }
                const float a0 = red16(hsum4(ac[0]));
                const float a1 = red16(hsum4(ac[1]));
                const float a2 = red16(hsum4(ac[2]));
                const float a3 = red16(hsum4(ac[3]));
                if (kc == 15) {
                    float* axp = ls_ax + (b * 16 + jp) * 4;
                    axp[0] = a0;
                    axp[1] = a1;
                    axp[2] = a2;
                    axp[3] = a3;
                }
            }
        }
    }
}

extern "C" void kernel_launch(void* const* d_in, const int* in_sizes, int n_in,
                              void* d_out, int out_size, void* d_ws, size_t ws_size,
                              hipStream_t stream) {
    const float* x   = (const float*)d_in[0];
    const float* Wih = (const float*)d_in[1];
    const float* Whh = (const float*)d_in[2];
    const float* bih = (const float*)d_in[3];
    const float* bhh = (const float*)d_in[4];
    float* out = (float*)d_out;

    float* h0 = (float*)d_ws;          // 3*BH
    float* h1 = h0 + 3 * BH;           // 3*BH
    int* flags = (int*)(h1 + 3 * BH);  // 512 ints, poison-proof (signed compare)

    hipLaunchKernelGGL(lstm_persist, dim3(512), dim3(256), 0, stream,
                       x, Wih, Whh, bih, bhh, out, h0, h1, flags);
}